// Round 1
// baseline (495.785 us; speedup 1.0000x reference)
//
#include <hip/hip_runtime.h>
#include <hip/hip_bf16.h>

// MultiLoraLinear: out[b,s,o] = sum_i x[b,s,i] * weight[adapter_ids[b], o, i]
// B=4, S=2048, IN=4096, OUT=4096, MAX_LORAS=8. fp32 in/out, bf16 MFMA compute.

#define SEQ    2048
#define IN_K   4096
#define OUT_N  4096

typedef __attribute__((ext_vector_type(8))) short  short8;   // bf16x8 MFMA frag
typedef __attribute__((ext_vector_type(4))) float  float4v;

constexpr int BM = 128, BN = 128, BK = 32;
constexpr int THREADS = 256;

// bf16 round-to-nearest-even from f32 (bit trick; inputs are finite)
__device__ inline short f2b(float f) {
    union { float f; unsigned u; } v; v.f = f;
    unsigned r = v.u + 0x7FFFu + ((v.u >> 16) & 1u);
    return (short)(r >> 16);
}

__device__ inline short8 pack8(float4v lo, float4v hi) {
    short8 r;
    r[0] = f2b(lo[0]); r[1] = f2b(lo[1]); r[2] = f2b(lo[2]); r[3] = f2b(lo[3]);
    r[4] = f2b(hi[0]); r[5] = f2b(hi[1]); r[6] = f2b(hi[2]); r[7] = f2b(hi[3]);
    return r;
}

// XOR swizzle of 16B slot within a 64B LDS row: bijective, ds_read <=2-way bank aliasing
__device__ inline int xr(int row) { return (row & 3) ^ ((row >> 2) & 3); }

__global__ __launch_bounds__(THREADS, 2)
void mll_gemm_kernel(const float* __restrict__ x,
                     const float* __restrict__ w,
                     const int*   __restrict__ adapter_ids,
                     float* __restrict__ out)
{
    __shared__ __align__(16) short As[2][BM * BK];
    __shared__ __align__(16) short Bs[2][BN * BK];

    const int tid  = threadIdx.x;
    const int lane = tid & 63;
    const int wave = tid >> 6;
    const int wr   = wave >> 1;   // 0..1 -> M half
    const int wc   = wave & 1;    // 0..1 -> N half

    const int b    = blockIdx.z;
    const int aid  = adapter_ids[b];
    const int brow = blockIdx.y * BM;   // S offset
    const int bcol = blockIdx.x * BN;   // OUT offset

    const float* __restrict__ xb = x + (size_t)b   * SEQ   * IN_K;
    const float* __restrict__ wb = w + (size_t)aid * OUT_N * IN_K;

    // staging registers: 2 groups x 2 float4 per operand
    float4v ra[2][2], rb[2][2];

    auto LOADG = [&](int kt) {
        const int k0 = kt * BK;
#pragma unroll
        for (int g = 0; g < 2; ++g) {
            const int f  = tid + g * THREADS;   // 0..511, unit = 8 f32
            const int r  = f >> 2;              // tile row 0..127
            const int sl = f & 3;               // 8-f32 slot within row
            const float* pa = xb + (size_t)(brow + r) * IN_K + k0 + sl * 8;
            ra[g][0] = *(const float4v*)pa;
            ra[g][1] = *(const float4v*)(pa + 4);
            const float* pb = wb + (size_t)(bcol + r) * IN_K + k0 + sl * 8;
            rb[g][0] = *(const float4v*)pb;
            rb[g][1] = *(const float4v*)(pb + 4);
        }
    };

    auto STORE_LDS = [&](int buf) {
#pragma unroll
        for (int g = 0; g < 2; ++g) {
            const int f  = tid + g * THREADS;
            const int r  = f >> 2;
            const int sl = f & 3;
            const int ss = sl ^ xr(r);
            *(short8*)&As[buf][r * BK + ss * 8] = pack8(ra[g][0], ra[g][1]);
            *(short8*)&Bs[buf][r * BK + ss * 8] = pack8(rb[g][0], rb[g][1]);
        }
    };

    float4v acc[4][4];
#pragma unroll
    for (int m = 0; m < 4; ++m)
#pragma unroll
        for (int n = 0; n < 4; ++n)
            acc[m][n] = (float4v){0.f, 0.f, 0.f, 0.f};

    const int NT = IN_K / BK;   // 128

    LOADG(0);
    STORE_LDS(0);
    __syncthreads();

    int cur = 0;
    for (int kt = 0; kt < NT; ++kt) {
        if (kt + 1 < NT) LOADG(kt + 1);   // issue next-tile global loads early

        // fragment reads from current buffer
        short8 af[4], bfr[4];
        const int ksl = lane >> 4;        // 16B k-slot 0..3
#pragma unroll
        for (int m = 0; m < 4; ++m) {
            const int rr = wr * 64 + m * 16 + (lane & 15);
            af[m] = *(const short8*)&As[cur][rr * BK + (ksl ^ xr(rr)) * 8];
        }
#pragma unroll
        for (int n = 0; n < 4; ++n) {
            const int rc = wc * 64 + n * 16 + (lane & 15);
            bfr[n] = *(const short8*)&Bs[cur][rc * BK + (ksl ^ xr(rc)) * 8];
        }
#pragma unroll
        for (int m = 0; m < 4; ++m)
#pragma unroll
            for (int n = 0; n < 4; ++n)
                acc[m][n] = __builtin_amdgcn_mfma_f32_16x16x32_bf16(
                    af[m], bfr[n], acc[m][n], 0, 0, 0);

        if (kt + 1 < NT) STORE_LDS(cur ^ 1);  // convert + write next buffer
        __syncthreads();
        cur ^= 1;
    }

    // epilogue: C/D layout col=lane&15, row=(lane>>4)*4+reg  [m89/m91]
    float* __restrict__ ob = out + (size_t)b * SEQ * OUT_N;
    const int lrow = (lane >> 4) * 4;
    const int lcol = lane & 15;
#pragma unroll
    for (int m = 0; m < 4; ++m) {
#pragma unroll
        for (int n = 0; n < 4; ++n) {
            const int r0 = brow + wr * 64 + m * 16 + lrow;
            const int c  = bcol + wc * 64 + n * 16 + lcol;
#pragma unroll
            for (int j = 0; j < 4; ++j)
                ob[(size_t)(r0 + j) * OUT_N + c] = acc[m][n][j];
        }
    }
}

extern "C" void kernel_launch(void* const* d_in, const int* in_sizes, int n_in,
                              void* d_out, int out_size, void* d_ws, size_t ws_size,
                              hipStream_t stream)
{
    const float* x   = (const float*)d_in[0];
    const float* w   = (const float*)d_in[1];
    const int*   ids = (const int*)d_in[2];
    float* out = (float*)d_out;

    dim3 grid(OUT_N / BN, SEQ / BM, 4);   // (32, 16, 4)
    dim3 block(THREADS);
    mll_gemm_kernel<<<grid, block, 0, stream>>>(x, w, ids, out);
}

// Round 2
// 431.784 us; speedup vs baseline: 1.1482x; 1.1482x over previous
//
#include <hip/hip_runtime.h>
#include <hip/hip_bf16.h>

// MultiLoraLinear: out[b,s,o] = sum_i x[b,s,i] * weight[adapter_ids[b], o, i]
// B=4, S=2048, IN=4096, OUT=4096. fp32 in/out, bf16 MFMA compute.
// Pipeline: (1) cvt x -> bf16 in ws, (2) gather+cvt 4 adapter mats -> bf16 in ws,
//           (3) m97-structure 128x128 GEMM with global_load_lds width=16.

#define SEQ    2048
#define IN_K   4096
#define OUT_N  4096
#define NB     4

typedef __attribute__((ext_vector_type(8))) short  short8;   // bf16x8 MFMA frag
typedef __attribute__((ext_vector_type(4))) float  float4v;

constexpr int BM = 128, BN = 128, BK = 32;
constexpr int THREADS = 256;

// bf16 round-to-nearest-even from f32 (bit trick; inputs finite)
__device__ inline short f2b(float f) {
    union { float f; unsigned u; } v; v.f = f;
    unsigned r = v.u + 0x7FFFu + ((v.u >> 16) & 1u);
    return (short)(r >> 16);
}

__device__ inline short8 pack8(float4v lo, float4v hi) {
    short8 r;
    r[0] = f2b(lo[0]); r[1] = f2b(lo[1]); r[2] = f2b(lo[2]); r[3] = f2b(lo[3]);
    r[4] = f2b(hi[0]); r[5] = f2b(hi[1]); r[6] = f2b(hi[2]); r[7] = f2b(hi[3]);
    return r;
}

typedef const __attribute__((address_space(1))) void* gp1_t;
typedef __attribute__((address_space(3))) void*       lp3_t;

__device__ inline void gload_lds16(const void* g, void* l) {
    __builtin_amdgcn_global_load_lds((gp1_t)g, (lp3_t)l, 16, 0, 0);
}

// ---------------- pass 1: x fp32 -> bf16 ----------------
__global__ __launch_bounds__(256)
void cvt_x_kernel(const float* __restrict__ x, short* __restrict__ o, int n8)
{
    int i = blockIdx.x * blockDim.x + threadIdx.x;
    const int stride = gridDim.x * blockDim.x;
    for (; i < n8; i += stride) {
        const float4v a = *(const float4v*)(x + (size_t)i * 8);
        const float4v b = *(const float4v*)(x + (size_t)i * 8 + 4);
        *(short8*)(o + (size_t)i * 8) = pack8(a, b);
    }
}

// ---------------- pass 2: gather w[ids[b]] fp32 -> bf16 ----------------
__global__ __launch_bounds__(256)
void cvt_w_kernel(const float* __restrict__ w, const int* __restrict__ ids,
                  short* __restrict__ o)
{
    const int b = blockIdx.y;
    const float* __restrict__ src = w + (size_t)ids[b] * OUT_N * IN_K;
    short* __restrict__ dst = o + (size_t)b * OUT_N * IN_K;
    const int n8 = OUT_N * IN_K / 8;
    int i = blockIdx.x * blockDim.x + threadIdx.x;
    const int stride = gridDim.x * blockDim.x;
    for (; i < n8; i += stride) {
        const float4v a = *(const float4v*)(src + (size_t)i * 8);
        const float4v c = *(const float4v*)(src + (size_t)i * 8 + 4);
        *(short8*)(dst + (size_t)i * 8) = pack8(a, c);
    }
}

// ---------------- pass 3: m97-structure bf16 GEMM ----------------
// A: [NB][SEQ][IN_K] bf16, W4: [NB][OUT_N][IN_K] bf16 (pre-gathered), out fp32.
__global__ __launch_bounds__(THREADS, 2)
void mll_gemm_bf16(const short* __restrict__ A, const short* __restrict__ W4,
                   float* __restrict__ out)
{
    __shared__ __align__(16) short As[BM * BK];   // 8 KB, linear row-major [128][32]
    __shared__ __align__(16) short Bs[BN * BK];   // 8 KB

    const int tid  = threadIdx.x;
    const int lane = tid & 63;
    const int wave = tid >> 6;
    const int wr   = wave >> 1;
    const int wc   = wave & 1;

    const int b    = blockIdx.z;
    const int brow = blockIdx.y * BM;
    const int bcol = blockIdx.x * BN;

    const short* __restrict__ Ab = A  + (size_t)b * SEQ   * IN_K;
    const short* __restrict__ Bb = W4 + (size_t)b * OUT_N * IN_K;

    // staging chunk ids: chunk c covers LDS bytes [c*16, c*16+16) == row c>>2, k-slot c&3
    const int c0 = tid, c1 = tid + THREADS;
    const short* pa0 = Ab + (size_t)(brow + (c0 >> 2)) * IN_K + (c0 & 3) * 8;
    const short* pa1 = Ab + (size_t)(brow + (c1 >> 2)) * IN_K + (c1 & 3) * 8;
    const short* pb0 = Bb + (size_t)(bcol + (c0 >> 2)) * IN_K + (c0 & 3) * 8;
    const short* pb1 = Bb + (size_t)(bcol + (c1 >> 2)) * IN_K + (c1 & 3) * 8;

    float4v acc[4][4];
#pragma unroll
    for (int m = 0; m < 4; ++m)
#pragma unroll
        for (int n = 0; n < 4; ++n)
            acc[m][n] = (float4v){0.f, 0.f, 0.f, 0.f};

    const int ksl = lane >> 4;      // 16B k-slot 0..3
    const int lr  = lane & 15;

    for (int kt = 0; kt < IN_K / BK; ++kt) {
        const int k0 = kt * BK;
        gload_lds16(pa0 + k0, &As[c0 * 8]);
        gload_lds16(pa1 + k0, &As[c1 * 8]);
        gload_lds16(pb0 + k0, &Bs[c0 * 8]);
        gload_lds16(pb1 + k0, &Bs[c1 * 8]);
        __syncthreads();            // drains vmcnt -> LDS tiles ready

        short8 af[4], bfr[4];
#pragma unroll
        for (int m = 0; m < 4; ++m)
            af[m] = *(const short8*)&As[(wr * 64 + m * 16 + lr) * BK + ksl * 8];
#pragma unroll
        for (int n = 0; n < 4; ++n)
            bfr[n] = *(const short8*)&Bs[(wc * 64 + n * 16 + lr) * BK + ksl * 8];

#pragma unroll
        for (int m = 0; m < 4; ++m)
#pragma unroll
            for (int n = 0; n < 4; ++n)
                acc[m][n] = __builtin_amdgcn_mfma_f32_16x16x32_bf16(
                    af[m], bfr[n], acc[m][n], 0, 0, 0);

        __syncthreads();            // protect LDS from next stage
    }

    // epilogue: C/D layout col=lane&15, row=(lane>>4)*4+reg  [m89/m91]
    float* __restrict__ ob = out + (size_t)b * SEQ * OUT_N;
    const int lrow = (lane >> 4) * 4;
#pragma unroll
    for (int m = 0; m < 4; ++m) {
#pragma unroll
        for (int n = 0; n < 4; ++n) {
            const int r0 = brow + wr * 64 + m * 16 + lrow;
            const int c  = bcol + wc * 64 + n * 16 + lr;
#pragma unroll
            for (int j = 0; j < 4; ++j)
                ob[(size_t)(r0 + j) * OUT_N + c] = acc[m][n][j];
        }
    }
}

// ---------------- fallback: round-1 fused kernel (ws too small) ----------------
__device__ inline int xr(int row) { return (row & 3) ^ ((row >> 2) & 3); }

__global__ __launch_bounds__(THREADS, 2)
void mll_gemm_fused(const float* __restrict__ x,
                    const float* __restrict__ w,
                    const int*   __restrict__ adapter_ids,
                    float* __restrict__ out)
{
    __shared__ __align__(16) short As[2][BM * BK];
    __shared__ __align__(16) short Bs[2][BN * BK];

    const int tid  = threadIdx.x;
    const int lane = tid & 63;
    const int wave = tid >> 6;
    const int wr   = wave >> 1;
    const int wc   = wave & 1;

    const int b    = blockIdx.z;
    const int aid  = adapter_ids[b];
    const int brow = blockIdx.y * BM;
    const int bcol = blockIdx.x * BN;

    const float* __restrict__ xb = x + (size_t)b   * SEQ   * IN_K;
    const float* __restrict__ wb = w + (size_t)aid * OUT_N * IN_K;

    float4v ra[2][2], rb[2][2];

    auto LOADG = [&](int kt) {
        const int k0 = kt * BK;
#pragma unroll
        for (int g = 0; g < 2; ++g) {
            const int f  = tid + g * THREADS;
            const int r  = f >> 2;
            const int sl = f & 3;
            const float* pa = xb + (size_t)(brow + r) * IN_K + k0 + sl * 8;
            ra[g][0] = *(const float4v*)pa;
            ra[g][1] = *(const float4v*)(pa + 4);
            const float* pb = wb + (size_t)(bcol + r) * IN_K + k0 + sl * 8;
            rb[g][0] = *(const float4v*)pb;
            rb[g][1] = *(const float4v*)(pb + 4);
        }
    };

    auto STORE_LDS = [&](int buf) {
#pragma unroll
        for (int g = 0; g < 2; ++g) {
            const int f  = tid + g * THREADS;
            const int r  = f >> 2;
            const int sl = f & 3;
            const int ss = sl ^ xr(r);
            *(short8*)&As[buf][r * BK + ss * 8] = pack8(ra[g][0], ra[g][1]);
            *(short8*)&Bs[buf][r * BK + ss * 8] = pack8(rb[g][0], rb[g][1]);
        }
    };

    float4v acc[4][4];
#pragma unroll
    for (int m = 0; m < 4; ++m)
#pragma unroll
        for (int n = 0; n < 4; ++n)
            acc[m][n] = (float4v){0.f, 0.f, 0.f, 0.f};

    const int NT = IN_K / BK;
    LOADG(0);
    STORE_LDS(0);
    __syncthreads();

    int cur = 0;
    for (int kt = 0; kt < NT; ++kt) {
        if (kt + 1 < NT) LOADG(kt + 1);
        short8 af[4], bfr[4];
        const int ksl = lane >> 4;
#pragma unroll
        for (int m = 0; m < 4; ++m) {
            const int rr = wr * 64 + m * 16 + (lane & 15);
            af[m] = *(const short8*)&As[cur][rr * BK + (ksl ^ xr(rr)) * 8];
        }
#pragma unroll
        for (int n = 0; n < 4; ++n) {
            const int rc = wc * 64 + n * 16 + (lane & 15);
            bfr[n] = *(const short8*)&Bs[cur][rc * BK + (ksl ^ xr(rc)) * 8];
        }
#pragma unroll
        for (int m = 0; m < 4; ++m)
#pragma unroll
            for (int n = 0; n < 4; ++n)
                acc[m][n] = __builtin_amdgcn_mfma_f32_16x16x32_bf16(
                    af[m], bfr[n], acc[m][n], 0, 0, 0);
        if (kt + 1 < NT) STORE_LDS(cur ^ 1);
        __syncthreads();
        cur ^= 1;
    }

    float* __restrict__ ob = out + (size_t)b * SEQ * OUT_N;
    const int lrow = (lane >> 4) * 4;
    const int lcol = lane & 15;
#pragma unroll
    for (int m = 0; m < 4; ++m) {
#pragma unroll
        for (int n = 0; n < 4; ++n) {
            const int r0 = brow + wr * 64 + m * 16 + lrow;
            const int c  = bcol + wc * 64 + n * 16 + lcol;
#pragma unroll
            for (int j = 0; j < 4; ++j)
                ob[(size_t)(r0 + j) * OUT_N + c] = acc[m][n][j];
        }
    }
}

extern "C" void kernel_launch(void* const* d_in, const int* in_sizes, int n_in,
                              void* d_out, int out_size, void* d_ws, size_t ws_size,
                              hipStream_t stream)
{
    const float* x   = (const float*)d_in[0];
    const float* w   = (const float*)d_in[1];
    const int*   ids = (const int*)d_in[2];
    float* out = (float*)d_out;

    const size_t xb_bytes = (size_t)NB * SEQ   * IN_K * sizeof(short);  //  64 MB
    const size_t wb_bytes = (size_t)NB * OUT_N * IN_K * sizeof(short);  // 128 MB

    if (ws_size >= xb_bytes + wb_bytes) {
        short* xb16 = (short*)d_ws;
        short* wb16 = (short*)((char*)d_ws + xb_bytes);
        cvt_x_kernel<<<2048, 256, 0, stream>>>(x, xb16, NB * SEQ * IN_K / 8);
        cvt_w_kernel<<<dim3(1024, NB), 256, 0, stream>>>(w, ids, wb16);
        mll_gemm_bf16<<<dim3(OUT_N / BN, SEQ / BM, NB), THREADS, 0, stream>>>(
            xb16, wb16, out);
    } else {
        mll_gemm_fused<<<dim3(OUT_N / BN, SEQ / BM, NB), THREADS, 0, stream>>>(
            x, w, ids, out);
    }
}

// Round 3
// 370.563 us; speedup vs baseline: 1.3379x; 1.1652x over previous
//
#include <hip/hip_runtime.h>
#include <hip/hip_bf16.h>

// MultiLoraLinear: out[b,s,o] = sum_i x[b,s,i] * weight[adapter_ids[b], o, i]
// B=4, S=2048, IN=4096, OUT=4096. fp32 in/out, bf16 MFMA compute.
// Pipeline: (1) cvt x -> bf16 ws, (2) gather+cvt adapters -> bf16 ws,
// (3) 256x256 GEMM, BK=32, depth-4 LDS ring, counted vmcnt(8) (T3+T4), setprio (T5).

#define SEQ    2048
#define IN_K   4096
#define OUT_N  4096
#define NB     4

typedef __attribute__((ext_vector_type(8))) short  short8;   // bf16x8 MFMA frag
typedef __attribute__((ext_vector_type(4))) float  float4v;

constexpr int BM = 256, BN = 256, BK = 32;
constexpr int GT = 512;                 // 8 waves
constexpr int KTILES = IN_K / BK;       // 128

// bf16 RNE from f32
__device__ inline short f2b(float f) {
    union { float f; unsigned u; } v; v.f = f;
    unsigned r = v.u + 0x7FFFu + ((v.u >> 16) & 1u);
    return (short)(r >> 16);
}
__device__ inline short8 pack8(float4v lo, float4v hi) {
    short8 r;
    r[0] = f2b(lo[0]); r[1] = f2b(lo[1]); r[2] = f2b(lo[2]); r[3] = f2b(lo[3]);
    r[4] = f2b(hi[0]); r[5] = f2b(hi[1]); r[6] = f2b(hi[2]); r[7] = f2b(hi[3]);
    return r;
}

typedef const __attribute__((address_space(1))) void* gp1_t;
typedef __attribute__((address_space(3))) void*       lp3_t;
__device__ inline void gload_lds16(const void* g, void* l) {
    __builtin_amdgcn_global_load_lds((gp1_t)g, (lp3_t)l, 16, 0, 0);
}

#define WAITV(N)  asm volatile("s_waitcnt vmcnt(" #N ")" ::: "memory")
#define WAITL0()  asm volatile("s_waitcnt lgkmcnt(0)" ::: "memory")

// ---------------- pass 1: x fp32 -> bf16 ----------------
__global__ __launch_bounds__(256)
void cvt_x_kernel(const float* __restrict__ x, short* __restrict__ o, int n8)
{
    int i = blockIdx.x * blockDim.x + threadIdx.x;
    const int stride = gridDim.x * blockDim.x;
    for (; i < n8; i += stride) {
        const float4v a = *(const float4v*)(x + (size_t)i * 8);
        const float4v b = *(const float4v*)(x + (size_t)i * 8 + 4);
        *(short8*)(o + (size_t)i * 8) = pack8(a, b);
    }
}

// ---------------- pass 2: gather w[ids[b]] fp32 -> bf16 ----------------
__global__ __launch_bounds__(256)
void cvt_w_kernel(const float* __restrict__ w, const int* __restrict__ ids,
                  short* __restrict__ o)
{
    const int b = blockIdx.y;
    const float* __restrict__ src = w + (size_t)ids[b] * OUT_N * IN_K;
    short* __restrict__ dst = o + (size_t)b * OUT_N * IN_K;
    const int n8 = OUT_N * IN_K / 8;
    int i = blockIdx.x * blockDim.x + threadIdx.x;
    const int stride = gridDim.x * blockDim.x;
    for (; i < n8; i += stride) {
        const float4v a = *(const float4v*)(src + (size_t)i * 8);
        const float4v c = *(const float4v*)(src + (size_t)i * 8 + 4);
        *(short8*)(dst + (size_t)i * 8) = pack8(a, c);
    }
}

// ---------------- pass 3: 256^2 counted-vmcnt ring GEMM ----------------
// A: [NB][SEQ][IN_K] bf16, W4: [NB][OUT_N][IN_K] bf16 (pre-gathered), out fp32.
__global__ __launch_bounds__(GT, 2)
void mll_gemm_8ph(const short* __restrict__ A, const short* __restrict__ W4,
                  float* __restrict__ out)
{
    // ring of 4 K-tile slots; slot s: A[256][32] bf16 then B[256][32] bf16 (32 KB each)
    __shared__ __align__(16) short lds[4][2 * BM * BK];   // 128 KiB

    const int tid  = threadIdx.x;
    const int lane = tid & 63;
    const int wid  = tid >> 6;    // 0..7
    const int wr   = wid >> 2;    // 0..1  (M half)
    const int wc   = wid & 3;     // 0..3  (N quarter)

    // chunked XCD swizzle (512 blocks, 512 % 8 == 0 -> bijective)
    const int bid = blockIdx.x;
    const int n   = (bid & 7) * 64 + (bid >> 3);
    const int bx  = n & 15;          // OUT tile
    const int by  = (n >> 4) & 7;    // SEQ tile
    const int bz  = n >> 7;          // batch
    const int brow = by * BM, bcol = bx * BN;

    const short* __restrict__ Ab = A  + (size_t)bz * SEQ   * IN_K + (size_t)brow * IN_K;
    const short* __restrict__ Bb = W4 + (size_t)bz * OUT_N * IN_K + (size_t)bcol * IN_K;

    // staging: per tile, per operand: 1024 x 16B chunks; thread covers c0=tid, c1=tid+512
    // chunk c -> row c>>2 (0..255), k-slot c&3; LDS dest linear at c*16 bytes.
    const int c0 = tid, c1 = tid + GT;
    const short* pa0 = Ab + (size_t)(c0 >> 2) * IN_K + (c0 & 3) * 8;
    const short* pa1 = Ab + (size_t)(c1 >> 2) * IN_K + (c1 & 3) * 8;
    const short* pb0 = Bb + (size_t)(c0 >> 2) * IN_K + (c0 & 3) * 8;
    const short* pb1 = Bb + (size_t)(c1 >> 2) * IN_K + (c1 & 3) * 8;

    float4v acc[8][4];
#pragma unroll
    for (int m = 0; m < 8; ++m)
#pragma unroll
        for (int q = 0; q < 4; ++q)
            acc[m][q] = (float4v){0.f, 0.f, 0.f, 0.f};

    const int lr  = lane & 15;
    const int ksl = lane >> 4;     // 16B k-slot 0..3

    // prologue: stage tiles 0,1,2 (12 loads/thread)
#pragma unroll
    for (int tt = 0; tt < 3; ++tt) {
        short* s = &lds[tt][0];
        gload_lds16(pa0 + tt * BK, s + c0 * 8);
        gload_lds16(pa1 + tt * BK, s + c1 * 8);
        gload_lds16(pb0 + tt * BK, s + BM * BK + c0 * 8);
        gload_lds16(pb1 + tt * BK, s + BM * BK + c1 * 8);
    }

    for (int t = 0; t < KTILES; ++t) {
        // boundary: certify tile t landed; leave tiles t+1,t+2 (8 loads) in flight
        if (t <= KTILES - 3)      WAITV(8);
        else if (t == KTILES - 2) WAITV(4);
        else                      WAITV(0);
        __builtin_amdgcn_s_barrier();

        const short* sA = &lds[t & 3][0];
        const short* sB = sA + BM * BK;
        short8 af[4], bf[4];

        // ---- phase 0: A m=0..3 + all B; stage A-chunks of tile t+3 ----
#pragma unroll
        for (int m = 0; m < 4; ++m)
            af[m] = *(const short8*)(sA + (wr * 128 + m * 16 + lr) * BK + ksl * 8);
#pragma unroll
        for (int q = 0; q < 4; ++q)
            bf[q] = *(const short8*)(sB + (wc * 64 + q * 16 + lr) * BK + ksl * 8);
        if (t <= KTILES - 4) {
            short* d = &lds[(t + 3) & 3][0];
            gload_lds16(pa0 + (t + 3) * BK, d + c0 * 8);
            gload_lds16(pa1 + (t + 3) * BK, d + c1 * 8);
        }
        WAITL0();
        __builtin_amdgcn_s_setprio(1);
#pragma unroll
        for (int m = 0; m < 4; ++m)
#pragma unroll
            for (int q = 0; q < 4; ++q)
                acc[m][q] = __builtin_amdgcn_mfma_f32_16x16x32_bf16(
                    af[m], bf[q], acc[m][q], 0, 0, 0);
        __builtin_amdgcn_s_setprio(0);
        __builtin_amdgcn_s_barrier();

        // ---- phase 1: A m=4..7; stage B-chunks of tile t+3 ----
#pragma unroll
        for (int m = 0; m < 4; ++m)
            af[m] = *(const short8*)(sA + (wr * 128 + (m + 4) * 16 + lr) * BK + ksl * 8);
        if (t <= KTILES - 4) {
            short* d = &lds[(t + 3) & 3][0];
            gload_lds16(pb0 + (t + 3) * BK, d + BM * BK + c0 * 8);
            gload_lds16(pb1 + (t + 3) * BK, d + BM * BK + c1 * 8);
        }
        WAITL0();
        __builtin_amdgcn_s_setprio(1);
#pragma unroll
        for (int m = 0; m < 4; ++m)
#pragma unroll
            for (int q = 0; q < 4; ++q)
                acc[m + 4][q] = __builtin_amdgcn_mfma_f32_16x16x32_bf16(
                    af[m], bf[q], acc[m + 4][q], 0, 0, 0);
        __builtin_amdgcn_s_setprio(0);
        // next iteration's boundary barrier closes this tile
    }

    // epilogue: C/D layout col=lane&15, row=(lane>>4)*4+reg
    float* __restrict__ ob = out + (size_t)bz * SEQ * OUT_N;
    const int lrow = ksl * 4;
#pragma unroll
    for (int m = 0; m < 8; ++m) {
#pragma unroll
        for (int q = 0; q < 4; ++q) {
            const int r0 = brow + wr * 128 + m * 16 + lrow;
            const int c  = bcol + wc * 64 + q * 16 + lr;
#pragma unroll
            for (int j = 0; j < 4; ++j)
                ob[(size_t)(r0 + j) * OUT_N + c] = acc[m][q][j];
        }
    }
}

// ---------------- fallback: fused kernel (ws too small) ----------------
__device__ inline int xr(int row) { return (row & 3) ^ ((row >> 2) & 3); }

__global__ __launch_bounds__(256, 2)
void mll_gemm_fused(const float* __restrict__ x,
                    const float* __restrict__ w,
                    const int*   __restrict__ adapter_ids,
                    float* __restrict__ out)
{
    constexpr int FBM = 128, FBN = 128, FBK = 32;
    __shared__ __align__(16) short As[2][FBM * FBK];
    __shared__ __align__(16) short Bs[2][FBN * FBK];

    const int tid  = threadIdx.x;
    const int lane = tid & 63;
    const int wave = tid >> 6;
    const int wr   = wave >> 1;
    const int wc   = wave & 1;

    const int b    = blockIdx.z;
    const int aid  = adapter_ids[b];
    const int brow = blockIdx.y * FBM;
    const int bcol = blockIdx.x * FBN;

    const float* __restrict__ xb = x + (size_t)b   * SEQ   * IN_K;
    const float* __restrict__ wb = w + (size_t)aid * OUT_N * IN_K;

    float4v ra[2][2], rb[2][2];

    auto LOADG = [&](int kt) {
        const int k0 = kt * FBK;
#pragma unroll
        for (int g = 0; g < 2; ++g) {
            const int f  = tid + g * 256;
            const int r  = f >> 2;
            const int sl = f & 3;
            const float* pa = xb + (size_t)(brow + r) * IN_K + k0 + sl * 8;
            ra[g][0] = *(const float4v*)pa;
            ra[g][1] = *(const float4v*)(pa + 4);
            const float* pb = wb + (size_t)(bcol + r) * IN_K + k0 + sl * 8;
            rb[g][0] = *(const float4v*)pb;
            rb[g][1] = *(const float4v*)(pb + 4);
        }
    };
    auto STORE_LDS = [&](int buf) {
#pragma unroll
        for (int g = 0; g < 2; ++g) {
            const int f  = tid + g * 256;
            const int r  = f >> 2;
            const int sl = f & 3;
            const int ss = sl ^ xr(r);
            *(short8*)&As[buf][r * FBK + ss * 8] = pack8(ra[g][0], ra[g][1]);
            *(short8*)&Bs[buf][r * FBK + ss * 8] = pack8(rb[g][0], rb[g][1]);
        }
    };

    float4v acc[4][4];
#pragma unroll
    for (int m = 0; m < 4; ++m)
#pragma unroll
        for (int q = 0; q < 4; ++q)
            acc[m][q] = (float4v){0.f, 0.f, 0.f, 0.f};

    const int NT = IN_K / FBK;
    LOADG(0); STORE_LDS(0); __syncthreads();
    int cur = 0;
    for (int kt = 0; kt < NT; ++kt) {
        if (kt + 1 < NT) LOADG(kt + 1);
        short8 af[4], bfr[4];
        const int ksl = lane >> 4;
#pragma unroll
        for (int m = 0; m < 4; ++m) {
            const int rr = wr * 64 + m * 16 + (lane & 15);
            af[m] = *(const short8*)&As[cur][rr * FBK + (ksl ^ xr(rr)) * 8];
        }
#pragma unroll
        for (int q = 0; q < 4; ++q) {
            const int rc = wc * 64 + q * 16 + (lane & 15);
            bfr[q] = *(const short8*)&Bs[cur][rc * FBK + (ksl ^ xr(rc)) * 8];
        }
#pragma unroll
        for (int m = 0; m < 4; ++m)
#pragma unroll
            for (int q = 0; q < 4; ++q)
                acc[m][q] = __builtin_amdgcn_mfma_f32_16x16x32_bf16(
                    af[m], bfr[q], acc[m][q], 0, 0, 0);
        if (kt + 1 < NT) STORE_LDS(cur ^ 1);
        __syncthreads();
        cur ^= 1;
    }

    float* __restrict__ ob = out + (size_t)b * SEQ * OUT_N;
    const int lrow = (lane >> 4) * 4;
    const int lcol = lane & 15;
#pragma unroll
    for (int m = 0; m < 4; ++m) {
#pragma unroll
        for (int q = 0; q < 4; ++q) {
            const int r0 = brow + wr * 64 + m * 16 + lrow;
            const int c  = bcol + wc * 64 + q * 16 + lcol;
#pragma unroll
            for (int j = 0; j < 4; ++j)
                ob[(size_t)(r0 + j) * OUT_N + c] = acc[m][q][j];
        }
    }
}

extern "C" void kernel_launch(void* const* d_in, const int* in_sizes, int n_in,
                              void* d_out, int out_size, void* d_ws, size_t ws_size,
                              hipStream_t stream)
{
    const float* x   = (const float*)d_in[0];
    const float* w   = (const float*)d_in[1];
    const int*   ids = (const int*)d_in[2];
    float* out = (float*)d_out;

    const size_t xb_bytes = (size_t)NB * SEQ   * IN_K * sizeof(short);  //  64 MB
    const size_t wb_bytes = (size_t)NB * OUT_N * IN_K * sizeof(short);  // 128 MB

    if (ws_size >= xb_bytes + wb_bytes) {
        short* xb16 = (short*)d_ws;
        short* wb16 = (short*)((char*)d_ws + xb_bytes);
        cvt_x_kernel<<<2048, 256, 0, stream>>>(x, xb16, NB * SEQ * IN_K / 8);
        cvt_w_kernel<<<dim3(1024, NB), 256, 0, stream>>>(w, ids, wb16);
        mll_gemm_8ph<<<512, GT, 0, stream>>>(xb16, wb16, out);
    } else {
        mll_gemm_fused<<<dim3(OUT_N / 128, SEQ / 128, NB), 256, 0, stream>>>(
            x, w, ids, out);
    }
}

// Round 4
// 339.067 us; speedup vs baseline: 1.4622x; 1.0929x over previous
//
#include <hip/hip_runtime.h>
#include <hip/hip_bf16.h>

// MultiLoraLinear: out[b,s,o] = sum_i x[b,s,i] * weight[adapter_ids[b], o, i]
// B=4, S=2048, IN=4096, OUT=4096. fp32 in/out, bf16 MFMA compute.
// (1) cvt x -> bf16 ws, (2) cvt referenced adapters -> bf16 id-slots (dedup),
// (3) 256x256 GEMM, BK=32, ring-4 LDS, pre-barrier ds_reads + WAITV(6) (T3+T4), setprio (T5).

#define SEQ    2048
#define IN_K   4096
#define OUT_N  4096
#define NB     4

typedef __attribute__((ext_vector_type(8))) short  short8;   // bf16x8 MFMA frag
typedef __attribute__((ext_vector_type(4))) float  float4v;

constexpr int BM = 256, BN = 256, BK = 32;
constexpr int GT = 512;                 // 8 waves
constexpr int KTILES = IN_K / BK;       // 128

// bf16 RNE from f32
__device__ inline short f2b(float f) {
    union { float f; unsigned u; } v; v.f = f;
    unsigned r = v.u + 0x7FFFu + ((v.u >> 16) & 1u);
    return (short)(r >> 16);
}
__device__ inline short8 pack8(float4v lo, float4v hi) {
    short8 r;
    r[0] = f2b(lo[0]); r[1] = f2b(lo[1]); r[2] = f2b(lo[2]); r[3] = f2b(lo[3]);
    r[4] = f2b(hi[0]); r[5] = f2b(hi[1]); r[6] = f2b(hi[2]); r[7] = f2b(hi[3]);
    return r;
}

typedef const __attribute__((address_space(1))) void* gp1_t;
typedef __attribute__((address_space(3))) void*       lp3_t;
__device__ inline void gload_lds16(const void* g, void* l) {
    __builtin_amdgcn_global_load_lds((gp1_t)g, (lp3_t)l, 16, 0, 0);
}

#define WAITV(N)  asm volatile("s_waitcnt vmcnt(" #N ")" ::: "memory")
#define WAITL0()  asm volatile("s_waitcnt lgkmcnt(0)" ::: "memory")

// ---------------- pass 1: x fp32 -> bf16 ----------------
__global__ __launch_bounds__(256)
void cvt_x_kernel(const float* __restrict__ x, short* __restrict__ o, int n8)
{
    int i = blockIdx.x * blockDim.x + threadIdx.x;
    const int stride = gridDim.x * blockDim.x;
    for (; i < n8; i += stride) {
        const float4v a = *(const float4v*)(x + (size_t)i * 8);
        const float4v b = *(const float4v*)(x + (size_t)i * 8 + 4);
        *(short8*)(o + (size_t)i * 8) = pack8(a, b);
    }
}

// ---------------- pass 2: cvt referenced adapters fp32 -> bf16 ----------------
// by_id=1: write to slot ids[b] (dedup via first-occurrence); else slot b (gather).
__global__ __launch_bounds__(256)
void cvt_w_kernel(const float* __restrict__ w, const int* __restrict__ ids,
                  short* __restrict__ o, int by_id)
{
    const int b  = blockIdx.y;
    const int id = ids[b];
    int slot = b;
    if (by_id) {
        for (int j = 0; j < b; ++j) if (ids[j] == id) return;  // dup: already handled
        slot = id;
    }
    const float* __restrict__ src = w + (size_t)id   * OUT_N * IN_K;
    short* __restrict__       dst = o + (size_t)slot * OUT_N * IN_K;
    const int n8 = OUT_N * IN_K / 8;
    int i = blockIdx.x * blockDim.x + threadIdx.x;
    const int stride = gridDim.x * blockDim.x;
    for (; i < n8; i += stride) {
        const float4v a = *(const float4v*)(src + (size_t)i * 8);
        const float4v c = *(const float4v*)(src + (size_t)i * 8 + 4);
        *(short8*)(dst + (size_t)i * 8) = pack8(a, c);
    }
}

// ---------------- pass 3: 256^2 ring-4 GEMM, pre-barrier reads ----------------
// A: [NB][SEQ][IN_K] bf16; W: bf16 adapter slots; slot = by_id ? ids[bz] : bz.
__global__ __launch_bounds__(GT, 2)
void mll_gemm_v4(const short* __restrict__ A, const short* __restrict__ W,
                 const int* __restrict__ ids, int by_id, float* __restrict__ out)
{
    // ring of 4 K-tile slots; slot s: A[256][32] bf16 then B[256][32] bf16 (32 KB)
    __shared__ __align__(16) short lds[4][2 * BM * BK];   // 128 KiB

    const int tid  = threadIdx.x;
    const int lane = tid & 63;
    const int wid  = tid >> 6;    // 0..7
    const int wr   = wid >> 2;    // 0..1  (M half)
    const int wc   = wid & 3;     // 0..3  (N quarter)

    // chunked XCD swizzle (512 blocks, 512 % 8 == 0 -> bijective)
    const int bid = blockIdx.x;
    const int n   = (bid & 7) * 64 + (bid >> 3);
    const int bx  = n & 15;          // OUT tile
    const int by  = (n >> 4) & 7;    // SEQ tile
    const int bz  = n >> 7;          // batch
    const int brow = by * BM, bcol = bx * BN;

    const int wslot = by_id ? ids[bz] : bz;
    const short* __restrict__ Ab = A + (size_t)bz * SEQ * IN_K + (size_t)brow * IN_K;
    const short* __restrict__ Bb = W + (size_t)wslot * OUT_N * IN_K + (size_t)bcol * IN_K;

    // staging: per tile per operand 1024 x 16B chunks; thread covers c0=tid, c1=tid+512
    // chunk c -> row c>>2, k-slot c&3; LDS dest linear at c*16 bytes.
    const int c0 = tid, c1 = tid + GT;
    const short* pa0 = Ab + (size_t)(c0 >> 2) * IN_K + (c0 & 3) * 8;
    const short* pa1 = Ab + (size_t)(c1 >> 2) * IN_K + (c1 & 3) * 8;
    const short* pb0 = Bb + (size_t)(c0 >> 2) * IN_K + (c0 & 3) * 8;
    const short* pb1 = Bb + (size_t)(c1 >> 2) * IN_K + (c1 & 3) * 8;

    float4v acc[8][4];
#pragma unroll
    for (int m = 0; m < 8; ++m)
#pragma unroll
        for (int q = 0; q < 4; ++q)
            acc[m][q] = (float4v){0.f, 0.f, 0.f, 0.f};

    const int lr  = lane & 15;
    const int ksl = lane >> 4;     // 16B k-slot 0..3

    // prologue: stage tiles 0,1,2 in order A(s),B(s)
#pragma unroll
    for (int tt = 0; tt < 3; ++tt) {
        short* s = &lds[tt][0];
        gload_lds16(pa0 + tt * BK, s + c0 * 8);
        gload_lds16(pa1 + tt * BK, s + c1 * 8);
        gload_lds16(pb0 + tt * BK, s + BM * BK + c0 * 8);
        gload_lds16(pb1 + tt * BK, s + BM * BK + c1 * 8);
    }
    WAITV(8);                       // drain tile 0 (leaves tiles 1,2 in flight)
    __builtin_amdgcn_s_barrier();   // tile 0 certified

    short8 af_a[4], af_b[4], bf[4];
    {   // initial reads0(0)
        const short* sA = &lds[0][0];
        const short* sB = sA + BM * BK;
#pragma unroll
        for (int m = 0; m < 4; ++m)
            af_a[m] = *(const short8*)(sA + (wr * 128 + m * 16 + lr) * BK + ksl * 8);
#pragma unroll
        for (int q = 0; q < 4; ++q)
            bf[q] = *(const short8*)(sB + (wc * 64 + q * 16 + lr) * BK + ksl * 8);
    }

    for (int t = 0; t < KTILES; ++t) {
        const short* sA = &lds[t & 3][0];

        // ---- phase A: MFMA m0..3; read af_b(t); stage A(t+3); certify t+1 ----
        WAITL0();
        __builtin_amdgcn_s_setprio(1);
#pragma unroll
        for (int m = 0; m < 4; ++m)
#pragma unroll
            for (int q = 0; q < 4; ++q)
                acc[m][q] = __builtin_amdgcn_mfma_f32_16x16x32_bf16(
                    af_a[m], bf[q], acc[m][q], 0, 0, 0);
        __builtin_amdgcn_s_setprio(0);
#pragma unroll
        for (int m = 0; m < 4; ++m)
            af_b[m] = *(const short8*)(sA + (wr * 128 + (m + 4) * 16 + lr) * BK + ksl * 8);
        if (t <= KTILES - 4) {      // stage A-half of tile t+3
            short* d = &lds[(t + 3) & 3][0];
            gload_lds16(pa0 + (t + 3) * BK, d + c0 * 8);
            gload_lds16(pa1 + (t + 3) * BK, d + c1 * 8);
        }
        if (t <= KTILES - 4)      WAITV(6);   // drain tile t+1's 4 loads (old, free)
        else if (t == KTILES - 3) WAITV(4);
        else if (t == KTILES - 2) WAITV(0);
        __builtin_amdgcn_s_barrier();          // tile t+1 certified for all waves

        // ---- phase B: MFMA m4..7; read af_a+bf(t+1); stage B(t+3) ----
        WAITL0();
        __builtin_amdgcn_s_setprio(1);
#pragma unroll
        for (int m = 0; m < 4; ++m)
#pragma unroll
            for (int q = 0; q < 4; ++q)
                acc[m + 4][q] = __builtin_amdgcn_mfma_f32_16x16x32_bf16(
                    af_b[m], bf[q], acc[m + 4][q], 0, 0, 0);
        __builtin_amdgcn_s_setprio(0);
        if (t < KTILES - 1) {
            const short* sN = &lds[(t + 1) & 3][0];
            const short* sNB = sN + BM * BK;
#pragma unroll
            for (int m = 0; m < 4; ++m)
                af_a[m] = *(const short8*)(sN + (wr * 128 + m * 16 + lr) * BK + ksl * 8);
#pragma unroll
            for (int q = 0; q < 4; ++q)
                bf[q] = *(const short8*)(sNB + (wc * 64 + q * 16 + lr) * BK + ksl * 8);
        }
        if (t <= KTILES - 4) {      // stage B-half of tile t+3
            short* d = &lds[(t + 3) & 3][0];
            gload_lds16(pb0 + (t + 3) * BK, d + BM * BK + c0 * 8);
            gload_lds16(pb1 + (t + 3) * BK, d + BM * BK + c1 * 8);
        }
        __builtin_amdgcn_s_barrier();
    }

    // epilogue: C/D layout col=lane&15, row=(lane>>4)*4+reg
    float* __restrict__ ob = out + (size_t)bz * SEQ * OUT_N;
    const int lrow = ksl * 4;
#pragma unroll
    for (int m = 0; m < 8; ++m) {
#pragma unroll
        for (int q = 0; q < 4; ++q) {
            const int r0 = brow + wr * 128 + m * 16 + lrow;
            const int c  = bcol + wc * 64 + q * 16 + lr;
#pragma unroll
            for (int j = 0; j < 4; ++j)
                ob[(size_t)(r0 + j) * OUT_N + c] = acc[m][q][j];
        }
    }
}

// ---------------- fallback: fused kernel (ws too small) ----------------
__device__ inline int xr(int row) { return (row & 3) ^ ((row >> 2) & 3); }

__global__ __launch_bounds__(256, 2)
void mll_gemm_fused(const float* __restrict__ x,
                    const float* __restrict__ w,
                    const int*   __restrict__ adapter_ids,
                    float* __restrict__ out)
{
    constexpr int FBM = 128, FBN = 128, FBK = 32;
    __shared__ __align__(16) short As[2][FBM * FBK];
    __shared__ __align__(16) short Bs[2][FBN * FBK];

    const int tid  = threadIdx.x;
    const int lane = tid & 63;
    const int wave = tid >> 6;
    const int wr   = wave >> 1;
    const int wc   = wave & 1;

    const int b    = blockIdx.z;
    const int aid  = adapter_ids[b];
    const int brow = blockIdx.y * FBM;
    const int bcol = blockIdx.x * FBN;

    const float* __restrict__ xb = x + (size_t)b   * SEQ   * IN_K;
    const float* __restrict__ wb = w + (size_t)aid * OUT_N * IN_K;

    float4v ra[2][2], rb[2][2];

    auto LOADG = [&](int kt) {
        const int k0 = kt * FBK;
#pragma unroll
        for (int g = 0; g < 2; ++g) {
            const int f  = tid + g * 256;
            const int r  = f >> 2;
            const int sl = f & 3;
            const float* pa = xb + (size_t)(brow + r) * IN_K + k0 + sl * 8;
            ra[g][0] = *(const float4v*)pa;
            ra[g][1] = *(const float4v*)(pa + 4);
            const float* pb = wb + (size_t)(bcol + r) * IN_K + k0 + sl * 8;
            rb[g][0] = *(const float4v*)pb;
            rb[g][1] = *(const float4v*)(pb + 4);
        }
    };
    auto STORE_LDS = [&](int buf) {
#pragma unroll
        for (int g = 0; g < 2; ++g) {
            const int f  = tid + g * 256;
            const int r  = f >> 2;
            const int sl = f & 3;
            const int ss = sl ^ xr(r);
            *(short8*)&As[buf][r * FBK + ss * 8] = pack8(ra[g][0], ra[g][1]);
            *(short8*)&Bs[buf][r * FBK + ss * 8] = pack8(rb[g][0], rb[g][1]);
        }
    };

    float4v acc[4][4];
#pragma unroll
    for (int m = 0; m < 4; ++m)
#pragma unroll
        for (int q = 0; q < 4; ++q)
            acc[m][q] = (float4v){0.f, 0.f, 0.f, 0.f};

    const int NT = IN_K / FBK;
    LOADG(0); STORE_LDS(0); __syncthreads();
    int cur = 0;
    for (int kt = 0; kt < NT; ++kt) {
        if (kt + 1 < NT) LOADG(kt + 1);
        short8 af[4], bfr[4];
        const int ksl = lane >> 4;
#pragma unroll
        for (int m = 0; m < 4; ++m) {
            const int rr = wr * 64 + m * 16 + (lane & 15);
            af[m] = *(const short8*)&As[cur][rr * FBK + (ksl ^ xr(rr)) * 8];
        }
#pragma unroll
        for (int q = 0; q < 4; ++q) {
            const int rc = wc * 64 + q * 16 + (lane & 15);
            bfr[q] = *(const short8*)&Bs[cur][rc * FBK + (ksl ^ xr(rc)) * 8];
        }
#pragma unroll
        for (int m = 0; m < 4; ++m)
#pragma unroll
            for (int q = 0; q < 4; ++q)
                acc[m][q] = __builtin_amdgcn_mfma_f32_16x16x32_bf16(
                    af[m], bfr[q], acc[m][q], 0, 0, 0);
        if (kt + 1 < NT) STORE_LDS(cur ^ 1);
        __syncthreads();
        cur ^= 1;
    }

    float* __restrict__ ob = out + (size_t)b * SEQ * OUT_N;
    const int lrow = (lane >> 4) * 4;
    const int lcol = lane & 15;
#pragma unroll
    for (int m = 0; m < 4; ++m) {
#pragma unroll
        for (int q = 0; q < 4; ++q) {
            const int r0 = brow + wr * 64 + m * 16 + lrow;
            const int c  = bcol + wc * 64 + q * 16 + lcol;
#pragma unroll
            for (int j = 0; j < 4; ++j)
                ob[(size_t)(r0 + j) * OUT_N + c] = acc[m][q][j];
        }
    }
}

extern "C" void kernel_launch(void* const* d_in, const int* in_sizes, int n_in,
                              void* d_out, int out_size, void* d_ws, size_t ws_size,
                              hipStream_t stream)
{
    const float* x   = (const float*)d_in[0];
    const float* w   = (const float*)d_in[1];
    const int*   ids = (const int*)d_in[2];
    float* out = (float*)d_out;

    const size_t xb_bytes   = (size_t)NB * SEQ   * IN_K * sizeof(short);  //  64 MB
    const size_t wb4_bytes  = (size_t)NB * OUT_N * IN_K * sizeof(short);  // 128 MB
    const size_t wb8_bytes  = (size_t)8  * OUT_N * IN_K * sizeof(short);  // 256 MB

    if (ws_size >= xb_bytes + wb8_bytes) {          // id-indexed slots + dedup
        short* xb16 = (short*)d_ws;
        short* wb16 = (short*)((char*)d_ws + xb_bytes);
        cvt_x_kernel<<<2048, 256, 0, stream>>>(x, xb16, NB * SEQ * IN_K / 8);
        cvt_w_kernel<<<dim3(1024, NB), 256, 0, stream>>>(w, ids, wb16, 1);
        mll_gemm_v4<<<512, GT, 0, stream>>>(xb16, wb16, ids, 1, out);
    } else if (ws_size >= xb_bytes + wb4_bytes) {   // per-batch gather
        short* xb16 = (short*)d_ws;
        short* wb16 = (short*)((char*)d_ws + xb_bytes);
        cvt_x_kernel<<<2048, 256, 0, stream>>>(x, xb16, NB * SEQ * IN_K / 8);
        cvt_w_kernel<<<dim3(1024, NB), 256, 0, stream>>>(w, ids, wb16, 0);
        mll_gemm_v4<<<512, GT, 0, stream>>>(xb16, wb16, ids, 0, out);
    } else {
        mll_gemm_fused<<<dim3(OUT_N / 128, SEQ / 128, NB), 256, 0, stream>>>(
            x, w, ids, out);
    }
}

// Round 5
// 336.825 us; speedup vs baseline: 1.4719x; 1.0067x over previous
//
#include <hip/hip_runtime.h>
#include <hip/hip_bf16.h>

// MultiLoraLinear: out[b,s,o] = sum_i x[b,s,i] * weight[adapter_ids[b], o, i]
// B=4, S=2048, IN=4096, OUT=4096. fp32 in/out, bf16 MFMA compute.
// (1) cvt x -> bf16 ws, (2) cvt referenced adapters -> bf16 id-slots (dedup),
// (3) 256x256 GEMM, BK=32, ring-4 LDS, counted vmcnt (T3+T4), setprio (T5),
//     + T2 granule swizzle: linear LDS dest, pre-swizzled global source, swizzled read.

#define SEQ    2048
#define IN_K   4096
#define OUT_N  4096
#define NB     4

typedef __attribute__((ext_vector_type(8))) short  short8;   // bf16x8 MFMA frag
typedef __attribute__((ext_vector_type(4))) float  float4v;

constexpr int BM = 256, BN = 256, BK = 32;
constexpr int GT = 512;                 // 8 waves
constexpr int KTILES = IN_K / BK;       // 128

// bf16 RNE from f32
__device__ inline short f2b(float f) {
    union { float f; unsigned u; } v; v.f = f;
    unsigned r = v.u + 0x7FFFu + ((v.u >> 16) & 1u);
    return (short)(r >> 16);
}
__device__ inline short8 pack8(float4v lo, float4v hi) {
    short8 r;
    r[0] = f2b(lo[0]); r[1] = f2b(lo[1]); r[2] = f2b(lo[2]); r[3] = f2b(lo[3]);
    r[4] = f2b(hi[0]); r[5] = f2b(hi[1]); r[6] = f2b(hi[2]); r[7] = f2b(hi[3]);
    return r;
}

typedef const __attribute__((address_space(1))) void* gp1_t;
typedef __attribute__((address_space(3))) void*       lp3_t;
__device__ inline void gload_lds16(const void* g, void* l) {
    __builtin_amdgcn_global_load_lds((gp1_t)g, (lp3_t)l, 16, 0, 0);
}

#define WAITV(N)  asm volatile("s_waitcnt vmcnt(" #N ")" ::: "memory")
#define WAITL0()  asm volatile("s_waitcnt lgkmcnt(0)" ::: "memory")

// ---------------- pass 1: x fp32 -> bf16 ----------------
__global__ __launch_bounds__(256)
void cvt_x_kernel(const float* __restrict__ x, short* __restrict__ o, int n8)
{
    int i = blockIdx.x * blockDim.x + threadIdx.x;
    const int stride = gridDim.x * blockDim.x;
    for (; i < n8; i += stride) {
        const float4v a = *(const float4v*)(x + (size_t)i * 8);
        const float4v b = *(const float4v*)(x + (size_t)i * 8 + 4);
        *(short8*)(o + (size_t)i * 8) = pack8(a, b);
    }
}

// ---------------- pass 2: cvt referenced adapters fp32 -> bf16 ----------------
// by_id=1: write to slot ids[b] (dedup via first-occurrence); else slot b (gather).
__global__ __launch_bounds__(256)
void cvt_w_kernel(const float* __restrict__ w, const int* __restrict__ ids,
                  short* __restrict__ o, int by_id)
{
    const int b  = blockIdx.y;
    const int id = ids[b];
    int slot = b;
    if (by_id) {
        for (int j = 0; j < b; ++j) if (ids[j] == id) return;  // dup: already handled
        slot = id;
    }
    const float* __restrict__ src = w + (size_t)id   * OUT_N * IN_K;
    short* __restrict__       dst = o + (size_t)slot * OUT_N * IN_K;
    const int n8 = OUT_N * IN_K / 8;
    int i = blockIdx.x * blockDim.x + threadIdx.x;
    const int stride = gridDim.x * blockDim.x;
    for (; i < n8; i += stride) {
        const float4v a = *(const float4v*)(src + (size_t)i * 8);
        const float4v c = *(const float4v*)(src + (size_t)i * 8 + 4);
        *(short8*)(dst + (size_t)i * 8) = pack8(a, c);
    }
}

// ---------------- pass 3: 256^2 ring-4 GEMM, swizzled LDS ----------------
// A: [NB][SEQ][IN_K] bf16; W: bf16 adapter slots; slot = by_id ? ids[bz] : bz.
// LDS granule swizzle: granule for (row, ksl) is row*4 + (ksl ^ ((row>>1)&3)).
// Staging keeps LDS dest linear and XORs the global source k-slot instead.
__global__ __launch_bounds__(GT, 2)
void mll_gemm_v5(const short* __restrict__ A, const short* __restrict__ W,
                 const int* __restrict__ ids, int by_id, float* __restrict__ out)
{
    // ring of 4 K-tile slots; slot s: A[256][32] bf16 then B[256][32] bf16 (32 KB)
    __shared__ __align__(16) short lds[4][2 * BM * BK];   // 128 KiB

    const int tid  = threadIdx.x;
    const int lane = tid & 63;
    const int wid  = tid >> 6;    // 0..7
    const int wr   = wid >> 2;    // 0..1  (M half)
    const int wc   = wid & 3;     // 0..3  (N quarter)

    // chunked XCD swizzle (512 blocks, 512 % 8 == 0 -> bijective)
    const int bid = blockIdx.x;
    const int n   = (bid & 7) * 64 + (bid >> 3);
    const int bx  = n & 15;          // OUT tile
    const int by  = (n >> 4) & 7;    // SEQ tile
    const int bz  = n >> 7;          // batch
    const int brow = by * BM, bcol = bx * BN;

    const int wslot = by_id ? ids[bz] : bz;
    const short* __restrict__ Ab = A + (size_t)bz * SEQ * IN_K + (size_t)brow * IN_K;
    const short* __restrict__ Bb = W + (size_t)wslot * OUT_N * IN_K + (size_t)bcol * IN_K;

    // staging: per tile per operand 1024 x 16B chunks; thread covers c0=tid, c1=tid+512
    // LDS chunk c (linear, granule c) holds global (row=c>>2, kslot=(c&3)^((row>>1)&3)).
    const int c0 = tid, c1 = tid + GT;
    const int r0_ = c0 >> 2, s0_ = (c0 & 3) ^ ((r0_ >> 1) & 3);
    const int r1_ = c1 >> 2, s1_ = (c1 & 3) ^ ((r1_ >> 1) & 3);
    const short* pa0 = Ab + (size_t)r0_ * IN_K + s0_ * 8;
    const short* pa1 = Ab + (size_t)r1_ * IN_K + s1_ * 8;
    const short* pb0 = Bb + (size_t)r0_ * IN_K + s0_ * 8;
    const short* pb1 = Bb + (size_t)r1_ * IN_K + s1_ * 8;

    float4v acc[8][4];
#pragma unroll
    for (int m = 0; m < 8; ++m)
#pragma unroll
        for (int q = 0; q < 4; ++q)
            acc[m][q] = (float4v){0.f, 0.f, 0.f, 0.f};

    const int lr  = lane & 15;
    const int ksl = lane >> 4;                      // 16B k-slot 0..3
    const int ks2 = (ksl ^ ((lr >> 1) & 3)) * 8;    // swizzled read k-offset (shorts)

    // prologue: stage tiles 0,1,2 in order A(s),B(s)
#pragma unroll
    for (int tt = 0; tt < 3; ++tt) {
        short* s = &lds[tt][0];
        gload_lds16(pa0 + tt * BK, s + c0 * 8);
        gload_lds16(pa1 + tt * BK, s + c1 * 8);
        gload_lds16(pb0 + tt * BK, s + BM * BK + c0 * 8);
        gload_lds16(pb1 + tt * BK, s + BM * BK + c1 * 8);
    }
    WAITV(8);                       // drain tile 0 (leaves tiles 1,2 in flight)
    __builtin_amdgcn_s_barrier();   // tile 0 certified

    short8 af_a[4], af_b[4], bf[4];
    {   // initial reads of tile 0
        const short* sA = &lds[0][0];
        const short* sB = sA + BM * BK;
#pragma unroll
        for (int m = 0; m < 4; ++m)
            af_a[m] = *(const short8*)(sA + (wr * 128 + m * 16 + lr) * BK + ks2);
#pragma unroll
        for (int q = 0; q < 4; ++q)
            bf[q] = *(const short8*)(sB + (wc * 64 + q * 16 + lr) * BK + ks2);
    }

    for (int t = 0; t < KTILES; ++t) {
        const short* sA = &lds[t & 3][0];

        // ---- phase A: MFMA m0..3; read af_b(t); stage A(t+3); certify t+1 ----
        WAITL0();
        __builtin_amdgcn_s_setprio(1);
#pragma unroll
        for (int m = 0; m < 4; ++m)
#pragma unroll
            for (int q = 0; q < 4; ++q)
                acc[m][q] = __builtin_amdgcn_mfma_f32_16x16x32_bf16(
                    af_a[m], bf[q], acc[m][q], 0, 0, 0);
        __builtin_amdgcn_s_setprio(0);
#pragma unroll
        for (int m = 0; m < 4; ++m)
            af_b[m] = *(const short8*)(sA + (wr * 128 + (m + 4) * 16 + lr) * BK + ks2);
        if (t <= KTILES - 4) {      // stage A-half of tile t+3
            short* d = &lds[(t + 3) & 3][0];
            gload_lds16(pa0 + (t + 3) * BK, d + c0 * 8);
            gload_lds16(pa1 + (t + 3) * BK, d + c1 * 8);
        }
        if (t <= KTILES - 4)      WAITV(6);   // drain tile t+1's loads (old, free)
        else if (t == KTILES - 3) WAITV(4);
        else if (t == KTILES - 2) WAITV(0);
        __builtin_amdgcn_s_barrier();          // tile t+1 certified for all waves

        // ---- phase B: MFMA m4..7; read af_a+bf(t+1); stage B(t+3) ----
        WAITL0();
        __builtin_amdgcn_s_setprio(1);
#pragma unroll
        for (int m = 0; m < 4; ++m)
#pragma unroll
            for (int q = 0; q < 4; ++q)
                acc[m + 4][q] = __builtin_amdgcn_mfma_f32_16x16x32_bf16(
                    af_b[m], bf[q], acc[m + 4][q], 0, 0, 0);
        __builtin_amdgcn_s_setprio(0);
        if (t < KTILES - 1) {
            const short* sN = &lds[(t + 1) & 3][0];
            const short* sNB = sN + BM * BK;
#pragma unroll
            for (int m = 0; m < 4; ++m)
                af_a[m] = *(const short8*)(sN + (wr * 128 + m * 16 + lr) * BK + ks2);
#pragma unroll
            for (int q = 0; q < 4; ++q)
                bf[q] = *(const short8*)(sNB + (wc * 64 + q * 16 + lr) * BK + ks2);
        }
        if (t <= KTILES - 4) {      // stage B-half of tile t+3
            short* d = &lds[(t + 3) & 3][0];
            gload_lds16(pb0 + (t + 3) * BK, d + BM * BK + c0 * 8);
            gload_lds16(pb1 + (t + 3) * BK, d + BM * BK + c1 * 8);
        }
        __builtin_amdgcn_s_barrier();
    }

    // epilogue: C/D layout col=lane&15, row=(lane>>4)*4+reg
    float* __restrict__ ob = out + (size_t)bz * SEQ * OUT_N;
    const int lrow = ksl * 4;
#pragma unroll
    for (int m = 0; m < 8; ++m) {
#pragma unroll
        for (int q = 0; q < 4; ++q) {
            const int r0 = brow + wr * 128 + m * 16 + lrow;
            const int c  = bcol + wc * 64 + q * 16 + lr;
#pragma unroll
            for (int j = 0; j < 4; ++j)
                ob[(size_t)(r0 + j) * OUT_N + c] = acc[m][q][j];
        }
    }
}

// ---------------- fallback: fused kernel (ws too small) ----------------
__device__ inline int xr(int row) { return (row & 3) ^ ((row >> 2) & 3); }

__global__ __launch_bounds__(256, 2)
void mll_gemm_fused(const float* __restrict__ x,
                    const float* __restrict__ w,
                    const int*   __restrict__ adapter_ids,
                    float* __restrict__ out)
{
    constexpr int FBM = 128, FBN = 128, FBK = 32;
    __shared__ __align__(16) short As[2][FBM * FBK];
    __shared__ __align__(16) short Bs[2][FBN * FBK];

    const int tid  = threadIdx.x;
    const int lane = tid & 63;
    const int wave = tid >> 6;
    const int wr   = wave >> 1;
    const int wc   = wave & 1;

    const int b    = blockIdx.z;
    const int aid  = adapter_ids[b];
    const int brow = blockIdx.y * FBM;
    const int bcol = blockIdx.x * FBN;

    const float* __restrict__ xb = x + (size_t)b   * SEQ   * IN_K;
    const float* __restrict__ wb = w + (size_t)aid * OUT_N * IN_K;

    float4v ra[2][2], rb[2][2];

    auto LOADG = [&](int kt) {
        const int k0 = kt * FBK;
#pragma unroll
        for (int g = 0; g < 2; ++g) {
            const int f  = tid + g * 256;
            const int r  = f >> 2;
            const int sl = f & 3;
            const float* pa = xb + (size_t)(brow + r) * IN_K + k0 + sl * 8;
            ra[g][0] = *(const float4v*)pa;
            ra[g][1] = *(const float4v*)(pa + 4);
            const float* pb = wb + (size_t)(bcol + r) * IN_K + k0 + sl * 8;
            rb[g][0] = *(const float4v*)pb;
            rb[g][1] = *(const float4v*)(pb + 4);
        }
    };
    auto STORE_LDS = [&](int buf) {
#pragma unroll
        for (int g = 0; g < 2; ++g) {
            const int f  = tid + g * 256;
            const int r  = f >> 2;
            const int sl = f & 3;
            const int ss = sl ^ xr(r);
            *(short8*)&As[buf][r * FBK + ss * 8] = pack8(ra[g][0], ra[g][1]);
            *(short8*)&Bs[buf][r * FBK + ss * 8] = pack8(rb[g][0], rb[g][1]);
        }
    };

    float4v acc[4][4];
#pragma unroll
    for (int m = 0; m < 4; ++m)
#pragma unroll
        for (int q = 0; q < 4; ++q)
            acc[m][q] = (float4v){0.f, 0.f, 0.f, 0.f};

    const int NT = IN_K / FBK;
    LOADG(0); STORE_LDS(0); __syncthreads();
    int cur = 0;
    for (int kt = 0; kt < NT; ++kt) {
        if (kt + 1 < NT) LOADG(kt + 1);
        short8 af[4], bfr[4];
        const int ksl = lane >> 4;
#pragma unroll
        for (int m = 0; m < 4; ++m) {
            const int rr = wr * 64 + m * 16 + (lane & 15);
            af[m] = *(const short8*)&As[cur][rr * FBK + (ksl ^ xr(rr)) * 8];
        }
#pragma unroll
        for (int q = 0; q < 4; ++q) {
            const int rc = wc * 64 + q * 16 + (lane & 15);
            bfr[q] = *(const short8*)&Bs[cur][rc * FBK + (ksl ^ xr(rc)) * 8];
        }
#pragma unroll
        for (int m = 0; m < 4; ++m)
#pragma unroll
            for (int q = 0; q < 4; ++q)
                acc[m][q] = __builtin_amdgcn_mfma_f32_16x16x32_bf16(
                    af[m], bfr[q], acc[m][q], 0, 0, 0);
        if (kt + 1 < NT) STORE_LDS(cur ^ 1);
        __syncthreads();
        cur ^= 1;
    }

    float* __restrict__ ob = out + (size_t)b * SEQ * OUT_N;
    const int lrow = (lane >> 4) * 4;
    const int lcol = lane & 15;
#pragma unroll
    for (int m = 0; m < 4; ++m) {
#pragma unroll
        for (int q = 0; q < 4; ++q) {
            const int r0 = brow + wr * 64 + m * 16 + lrow;
            const int c  = bcol + wc * 64 + q * 16 + lcol;
#pragma unroll
            for (int j = 0; j < 4; ++j)
                ob[(size_t)(r0 + j) * OUT_N + c] = acc[m][q][j];
        }
    }
}

extern "C" void kernel_launch(void* const* d_in, const int* in_sizes, int n_in,
                              void* d_out, int out_size, void* d_ws, size_t ws_size,
                              hipStream_t stream)
{
    const float* x   = (const float*)d_in[0];
    const float* w   = (const float*)d_in[1];
    const int*   ids = (const int*)d_in[2];
    float* out = (float*)d_out;

    const size_t xb_bytes   = (size_t)NB * SEQ   * IN_K * sizeof(short);  //  64 MB
    const size_t wb4_bytes  = (size_t)NB * OUT_N * IN_K * sizeof(short);  // 128 MB
    const size_t wb8_bytes  = (size_t)8  * OUT_N * IN_K * sizeof(short);  // 256 MB

    if (ws_size >= xb_bytes + wb8_bytes) {          // id-indexed slots + dedup
        short* xb16 = (short*)d_ws;
        short* wb16 = (short*)((char*)d_ws + xb_bytes);
        cvt_x_kernel<<<2048, 256, 0, stream>>>(x, xb16, NB * SEQ * IN_K / 8);
        cvt_w_kernel<<<dim3(1024, NB), 256, 0, stream>>>(w, ids, wb16, 1);
        mll_gemm_v5<<<512, GT, 0, stream>>>(xb16, wb16, ids, 1, out);
    } else if (ws_size >= xb_bytes + wb4_bytes) {   // per-batch gather
        short* xb16 = (short*)d_ws;
        short* wb16 = (short*)((char*)d_ws + xb_bytes);
        cvt_x_kernel<<<2048, 256, 0, stream>>>(x, xb16, NB * SEQ * IN_K / 8);
        cvt_w_kernel<<<dim3(1024, NB), 256, 0, stream>>>(w, ids, wb16, 0);
        mll_gemm_v5<<<512, GT, 0, stream>>>(xb16, wb16, ids, 0, out);
    } else {
        mll_gemm_fused<<<dim3(OUT_N / 128, SEQ / 128, NB), 256, 0, stream>>>(
            x, w, ids, out);
    }
}